// Round 1
// baseline (153.776 us; speedup 1.0000x reference)
//
#include <hip/hip_runtime.h>
#include <math.h>

#define EPS 1e-12f

// ---------------------------------------------------------------------------
// Workspace layout (floats):
//   Wt   [576][128]  @ 0        (pre-normalized, transposed weights)
//   expo [128]       @ 73728
//   s    [16*64*64]  @ 73856    (per-pixel channel sq-sum)
//   xinv [16*64*64]  @ 139392   (1/(sqrt(box3x3(s)+eps)+scale))
// total 204928 floats = 819712 B
// ---------------------------------------------------------------------------

// One wave per v: lane c in [0,64) reads 9 weights, reduces sum of squares,
// writes Wt[k=c*9+l][v] = w[v][c][l] / (sqrt(sum)+scale).
__global__ __launch_bounds__(256) void prep_weights(
    const float* __restrict__ w, const float* __restrict__ q,
    float* __restrict__ Wt) {
  int tid = threadIdx.x;
  int v = blockIdx.x * 4 + (tid >> 6);   // 32 blocks * 4 waves = 128 v
  int lane = tid & 63;                   // = channel c
  float qn = q[0] * 0.01f;
  float scale = qn * qn;

  const float* wp = w + v * 576 + lane * 9;
  float vals[9];
  float ss = 0.f;
#pragma unroll
  for (int j = 0; j < 9; ++j) { vals[j] = wp[j]; ss += vals[j] * vals[j]; }
#pragma unroll
  for (int off = 32; off > 0; off >>= 1) ss += __shfl_xor(ss, off);
  float inv = 1.0f / (sqrtf(ss + EPS) + scale);
#pragma unroll
  for (int j = 0; j < 9; ++j) Wt[(lane * 9 + j) * 128 + v] = vals[j] * inv;
}

__global__ void prep_expo(const float* __restrict__ p, float* __restrict__ expo) {
  int v = threadIdx.x;
  float t = p[v] * 0.1f;   // p / P_SCALE
  expo[v] = t * t;
}

// s[n,h,w] = sum_c x[n,c,h,w]^2
__global__ __launch_bounds__(256) void prep_s(
    const float* __restrict__ x, float* __restrict__ s) {
  int i = blockIdx.x * 256 + threadIdx.x;   // 65536 pixels
  int n = i >> 12;
  int hw = i & 4095;
  const float* xp = x + n * 262144 + hw;
  float acc = 0.f;
#pragma unroll 8
  for (int c = 0; c < 64; ++c) {
    float v = xp[c * 4096];
    acc += v * v;
  }
  s[i] = acc;
}

// xinv[n,h,w] = 1 / (sqrt(box3x3(s) + eps) + scale)
__global__ __launch_bounds__(256) void prep_xinv(
    const float* __restrict__ s, const float* __restrict__ q,
    float* __restrict__ xinv) {
  int i = blockIdx.x * 256 + threadIdx.x;
  int n = i >> 12;
  int h = (i >> 6) & 63;
  int w = i & 63;
  float qn = q[0] * 0.01f;
  float scale = qn * qn;
  const float* sp = s + n * 4096;
  float acc = 0.f;
#pragma unroll
  for (int a = -1; a <= 1; ++a) {
#pragma unroll
    for (int b = -1; b <= 1; ++b) {
      int hh = h + a, ww = w + b;
      if (hh >= 0 && hh < 64 && ww >= 0 && ww < 64) acc += sp[hh * 64 + ww];
    }
  }
  xinv[i] = 1.0f / (sqrtf(acc + EPS) + scale);
}

// Main conv: tile = 4(h) x 16(w) pixels, all 128 v. 256 threads.
// thread: vg = tid>>4 (8 v's), pg = tid&15 (w column), 4 rows -> 32 acc.
#define CK 8
__global__ __launch_bounds__(256) void conv_main(
    const float* __restrict__ x, const float* __restrict__ Wt,
    const float* __restrict__ expo, const float* __restrict__ xinv,
    float* __restrict__ out) {
  __shared__ float sA[CK][6][18];
  __shared__ float sB[CK * 9][128];

  int b = blockIdx.x;              // 1024 = 16 n * 16 th * 4 tw
  int n = b >> 6;
  int rem = b & 63;
  int th = rem >> 2;               // 0..15
  int tw = rem & 3;                // 0..3
  int gh = th * 4, gw = tw * 16;

  int tid = threadIdx.x;
  int vg = tid >> 4;               // 0..15 -> v0 = vg*8
  int pg = tid & 15;               // w offset within tile
  int v0 = vg * 8;

  float acc[4][8];
#pragma unroll
  for (int i = 0; i < 4; ++i)
#pragma unroll
    for (int j = 0; j < 8; ++j) acc[i][j] = 0.f;

  const float* xn = x + n * 262144;

  for (int c0 = 0; c0 < 64; c0 += CK) {
    // stage A: halo [CK][6][18]
    for (int idx = tid; idx < CK * 108; idx += 256) {
      int c = idx / 108;
      int r = (idx % 108) / 18;
      int col = idx % 18;
      int gy = gh + r - 1, gx = gw + col - 1;
      float v = 0.f;
      if (gy >= 0 && gy < 64 && gx >= 0 && gx < 64)
        v = xn[(c0 + c) * 4096 + gy * 64 + gx];
      sA[c][r][col] = v;
    }
    // stage B: CK*9 rows of 128 = 2304 float4, 9 per thread
    const float4* Bsrc = (const float4*)(Wt + c0 * 9 * 128);
    float4* Bdst = (float4*)&sB[0][0];
#pragma unroll
    for (int i = 0; i < 9; ++i) Bdst[tid + i * 256] = Bsrc[tid + i * 256];
    __syncthreads();

#pragma unroll
    for (int c = 0; c < CK; ++c) {
      float areg[6][3];
#pragma unroll
      for (int r = 0; r < 6; ++r)
#pragma unroll
        for (int j = 0; j < 3; ++j) areg[r][j] = sA[c][r][pg + j];
#pragma unroll
      for (int a = 0; a < 3; ++a) {
#pragma unroll
        for (int b2 = 0; b2 < 3; ++b2) {
          const float* Brow = &sB[c * 9 + a * 3 + b2][v0];
          float4 wlo = *(const float4*)Brow;
          float4 whi = *(const float4*)(Brow + 4);
#pragma unroll
          for (int pi = 0; pi < 4; ++pi) {
            float av = areg[pi + a][b2];
            acc[pi][0] += av * wlo.x;
            acc[pi][1] += av * wlo.y;
            acc[pi][2] += av * wlo.z;
            acc[pi][3] += av * wlo.w;
            acc[pi][4] += av * whi.x;
            acc[pi][5] += av * whi.y;
            acc[pi][6] += av * whi.z;
            acc[pi][7] += av * whi.w;
          }
        }
      }
    }
    __syncthreads();
  }

  // epilogue
  int hw0 = gh * 64 + gw + pg;
  float xi[4];
#pragma unroll
  for (int pi = 0; pi < 4; ++pi) xi[pi] = xinv[n * 4096 + hw0 + pi * 64];
  float ev[8];
#pragma unroll
  for (int vv = 0; vv < 8; ++vv) ev[vv] = expo[v0 + vv];

#pragma unroll
  for (int vv = 0; vv < 8; ++vv) {
    float e = ev[vv];
    float* op = out + (n * 128 + v0 + vv) * 4096 + hw0;
#pragma unroll
    for (int pi = 0; pi < 4; ++pi) {
      float y = acc[pi][vv] * xi[pi];
      float t = fabsf(y) + EPS;
      float r = exp2f(e * log2f(t));
      op[pi * 64] = (y == 0.0f) ? 0.0f : copysignf(r, y);
    }
  }
}

extern "C" void kernel_launch(void* const* d_in, const int* in_sizes, int n_in,
                              void* d_out, int out_size, void* d_ws, size_t ws_size,
                              hipStream_t stream) {
  const float* x = (const float*)d_in[0];      // [16,64,64,64]
  const float* w = (const float*)d_in[1];      // [128,64,9]
  const float* p = (const float*)d_in[2];      // [128]
  const float* q = (const float*)d_in[3];      // [1]
  float* out = (float*)d_out;                  // [16,128,64,64]
  float* ws = (float*)d_ws;

  float* Wt   = ws;             // 73728
  float* expo = ws + 73728;     // 128
  float* s    = ws + 73856;     // 65536
  float* xinv = ws + 139392;    // 65536

  prep_weights<<<32, 256, 0, stream>>>(w, q, Wt);
  prep_expo<<<1, 128, 0, stream>>>(p, expo);
  prep_s<<<256, 256, 0, stream>>>(x, s);
  prep_xinv<<<256, 256, 0, stream>>>(s, q, xinv);
  conv_main<<<1024, 256, 0, stream>>>(x, Wt, expo, xinv, out);
}

// Round 2
// 41.638 us; speedup vs baseline: 3.6931x; 3.6931x over previous
//
#include <hip/hip_runtime.h>
#include <math.h>
#include <stdint.h>

#define EPS 1e-12f

typedef __attribute__((ext_vector_type(8))) short short8v;   // 8 bf16 in 4 VGPRs
typedef __attribute__((ext_vector_type(8))) unsigned short us8;
typedef __attribute__((ext_vector_type(4))) float f32x4;

__device__ __forceinline__ unsigned short f2bf(float f) {
  union { float f; uint32_t u; } c; c.f = f;
  uint32_t u = c.u;
  uint32_t r = (u + 0x7FFFu + ((u >> 16) & 1u)) >> 16;  // RNE
  return (unsigned short)r;
}

__device__ __forceinline__ void gl_lds16(const void* g, void* l) {
  __builtin_amdgcn_global_load_lds(
      (const __attribute__((address_space(1))) unsigned int*)g,
      (__attribute__((address_space(3))) unsigned int*)l, 16, 0, 0);
}

// ---------------------------------------------------------------------------
// Workspace layout (bytes):
//   xT   [16][64][64][64] bf16 @ 0         (8,388,608)  swizzled c-chunks by w&7
//   Wb   [9][128][64] bf16    @ 8388608    (147,456)    swizzled c-chunks by v&7
//   expo [128] f32            @ 8536064    (512)
//   s    [65536] f32          @ 8536576    (262,144)
//   xinv [65536] f32          @ 8798720    (262,144)
// ---------------------------------------------------------------------------

// Normalize weights, reorder to Wb[l][v][c] bf16 with chunk-XOR swizzle.
__global__ __launch_bounds__(256) void prep_wb(
    const float* __restrict__ w, const float* __restrict__ q,
    unsigned short* __restrict__ Wb) {
  int tid = threadIdx.x;
  int v = blockIdx.x * 4 + (tid >> 6);
  int c = tid & 63;
  float qn = q[0] * 0.01f;
  float scale = qn * qn;
  const float* wp = w + (v * 64 + c) * 9;
  float vals[9];
  float ss = 0.f;
#pragma unroll
  for (int j = 0; j < 9; ++j) { vals[j] = wp[j]; ss += vals[j] * vals[j]; }
#pragma unroll
  for (int off = 32; off > 0; off >>= 1) ss += __shfl_xor(ss, off);
  float inv = 1.0f / (sqrtf(ss + EPS) + scale);
  int pos = (((c >> 3) ^ (v & 7)) << 3) | (c & 7);
#pragma unroll
  for (int j = 0; j < 9; ++j) Wb[(j * 128 + v) * 64 + pos] = f2bf(vals[j] * inv);
}

__global__ void prep_expo(const float* __restrict__ p, float* __restrict__ expo) {
  int v = threadIdx.x;
  float t = p[v] * 0.1f;
  expo[v] = t * t;
}

// Transpose x[n][c][h][w] fp32 -> xT[n][h][w][c] bf16 (chunk-swizzled by w&7),
// fused per-pixel channel square-sum s[n,h,w].
__global__ __launch_bounds__(256) void prep_xt(
    const float* __restrict__ x, unsigned short* __restrict__ xT,
    float* __restrict__ s) {
  __shared__ float tile[64][65];
  int b = blockIdx.x;           // n*64 + h
  int n = b >> 6, h = b & 63;
  int tid = threadIdx.x;
  int c = tid >> 2, q = tid & 3;
  const float* xp = x + ((size_t)(n * 64 + c)) * 4096 + h * 64;
#pragma unroll
  for (int k = 0; k < 4; ++k) {
    int w0 = q * 16 + k * 4;
    float4 v4 = *(const float4*)(xp + w0);
    tile[c][w0 + 0] = v4.x; tile[c][w0 + 1] = v4.y;
    tile[c][w0 + 2] = v4.z; tile[c][w0 + 3] = v4.w;
  }
  __syncthreads();
  int w = tid >> 2;
  float ss = 0.f;
  unsigned short* orow = xT + ((size_t)(n * 4096 + h * 64 + w)) * 64;
#pragma unroll
  for (int t = 0; t < 2; ++t) {
    int slot = q * 2 + t;
    int lc = slot ^ (w & 7);          // logical chunk stored in this slot
    us8 st;
#pragma unroll
    for (int e = 0; e < 8; ++e) {
      float f = tile[lc * 8 + e][w];
      ss += f * f;
      st[e] = f2bf(f);
    }
    *(us8*)(orow + slot * 8) = st;
  }
  ss += __shfl_xor(ss, 1);
  ss += __shfl_xor(ss, 2);
  if (q == 0) s[n * 4096 + h * 64 + w] = ss;
}

// xinv[n,h,w] = 1 / (sqrt(box3x3(s) + eps) + scale)
__global__ __launch_bounds__(256) void prep_xinv(
    const float* __restrict__ s, const float* __restrict__ q,
    float* __restrict__ xinv) {
  int i = blockIdx.x * 256 + threadIdx.x;
  int n = i >> 12;
  int h = (i >> 6) & 63;
  int w = i & 63;
  float qn = q[0] * 0.01f;
  float scale = qn * qn;
  const float* sp = s + n * 4096;
  float acc = 0.f;
#pragma unroll
  for (int a = -1; a <= 1; ++a) {
#pragma unroll
    for (int b = -1; b <= 1; ++b) {
      int hh = h + a, ww = w + b;
      if (hh >= 0 && hh < 64 && ww >= 0 && ww < 64) acc += sp[hh * 64 + ww];
    }
  }
  xinv[i] = 1.0f / (sqrtf(acc + EPS) + scale);
}

// Main MFMA conv: block = 256 thr (4 waves), tile = 128 v x 128 pixels
// (2 h-rows x 64 w). K = 9 shifts x 64 c. D[v][pixel] orientation.
__global__ __launch_bounds__(256, 2) void conv_mfma(
    const unsigned short* __restrict__ xT, const unsigned short* __restrict__ Wb,
    const float* __restrict__ expo, const float* __restrict__ xinv,
    float* __restrict__ out) {
  __shared__ unsigned short xs[4 * 64 * 64];   // 4 h-rows x 64 w x 64 c, 32 KB
  __shared__ unsigned short wl[2 * 128 * 64];  // double-buffered weights, 32 KB

  int b = blockIdx.x;            // 512 = 16 n x 32 row-pairs
  int n = b >> 5, hg = b & 31;
  int h0 = hg * 2;
  int tid = threadIdx.x;
  int lane = tid & 63, wid = tid >> 6;
  int wv = wid & 1, wp = wid >> 1;   // v-half, pixel-row
  int lp = lane & 15, lg = lane >> 4;

  // stage xs: wave wid stages tile row wid = image row h0-1+wid (zeros if OOB)
  {
    int hh = h0 - 1 + wid;
    unsigned short* dst = xs + wid * 4096;
    if (hh >= 0 && hh < 64) {
      const unsigned short* src = xT + ((size_t)(n * 4096 + hh * 64)) * 64;
#pragma unroll
      for (int i = 0; i < 8; ++i)
        gl_lds16(src + i * 512 + lane * 8, dst + i * 512);
    } else {
      us8 z = {};
#pragma unroll
      for (int i = 0; i < 8; ++i)
        *(us8*)(dst + i * 512 + lane * 8) = z;
    }
  }

  auto stage_w = [&](int bufi, int l) {
    const unsigned short* src = Wb + l * 8192 + wid * 2048;
    unsigned short* dst = wl + bufi * 8192 + wid * 2048;
#pragma unroll
    for (int i = 0; i < 4; ++i)
      gl_lds16(src + i * 512 + lane * 8, dst + i * 512);
  };
  stage_w(0, 0);

  f32x4 acc[4][4];
#pragma unroll
  for (int i = 0; i < 4; ++i)
#pragma unroll
    for (int j = 0; j < 4; ++j) acc[i][j] = (f32x4){0.f, 0.f, 0.f, 0.f};

  __syncthreads();   // xs + wl[0] ready (compiler drains vmcnt before barrier)

  int buf = 0;
#pragma unroll
  for (int l = 0; l < 9; ++l) {
    if (l < 8) stage_w(buf ^ 1, l + 1);   // prefetch next shift's weights
    const int a = l / 3, bs = l % 3;
    const unsigned short* xrow = xs + (wp + a) * 4096;
    const unsigned short* wrow = wl + buf * 8192 + wv * 4096;
#pragma unroll
    for (int half = 0; half < 2; ++half) {
      const int cbase = half * 4;          // chunk index base (c0/8)
      short8v av[4], bv[4];
#pragma unroll
      for (int vg = 0; vg < 4; ++vg) {
        int vloc = vg * 16 + lp;           // v & 7 == lane & 7
        int slot = (cbase + lg) ^ (lane & 7);
        av[vg] = *(const short8v*)(wrow + vloc * 64 + slot * 8);
      }
#pragma unroll
      for (int pg = 0; pg < 4; ++pg) {
        int wx = pg * 16 + lp + bs - 1;
        bool ok = (unsigned)wx < 64u;
        int wxc = ok ? wx : (wx < 0 ? 0 : 63);
        int slot = (cbase + lg) ^ (wxc & 7);
        short8v t = *(const short8v*)(xrow + wxc * 64 + slot * 8);
        short8v z = {};
        bv[pg] = ok ? t : z;
      }
#pragma unroll
      for (int vg = 0; vg < 4; ++vg)
#pragma unroll
        for (int pg = 0; pg < 4; ++pg)
          acc[vg][pg] = __builtin_amdgcn_mfma_f32_16x16x32_bf16(
              av[vg], bv[pg], acc[vg][pg], 0, 0, 0);
    }
    __syncthreads();
    buf ^= 1;
  }

  // epilogue: y = acc * xinv[pixel]; out = sign(y)*(|y|+eps)^expo[v]
  int h = h0 + wp;
  float xiv[4];
#pragma unroll
  for (int pg = 0; pg < 4; ++pg) xiv[pg] = xinv[n * 4096 + h * 64 + pg * 16 + lp];
#pragma unroll
  for (int vg = 0; vg < 4; ++vg) {
#pragma unroll
    for (int r = 0; r < 4; ++r) {
      int v = wv * 64 + vg * 16 + lg * 4 + r;
      float e = expo[v];
      float* op = out + ((size_t)(n * 128 + v)) * 4096 + h * 64 + lp;
#pragma unroll
      for (int pg = 0; pg < 4; ++pg) {
        float y = acc[vg][pg][r] * xiv[pg];
        float t = fabsf(y) + EPS;
        float rv = exp2f(e * log2f(t));
        op[pg * 16] = (y == 0.0f) ? 0.0f : copysignf(rv, y);
      }
    }
  }
}

extern "C" void kernel_launch(void* const* d_in, const int* in_sizes, int n_in,
                              void* d_out, int out_size, void* d_ws, size_t ws_size,
                              hipStream_t stream) {
  const float* x = (const float*)d_in[0];   // [16,64,64,64]
  const float* w = (const float*)d_in[1];   // [128,64,9]
  const float* p = (const float*)d_in[2];   // [128]
  const float* q = (const float*)d_in[3];   // [1]
  float* out = (float*)d_out;               // [16,128,64,64]

  char* wsb = (char*)d_ws;
  unsigned short* xT = (unsigned short*)(wsb);
  unsigned short* Wb = (unsigned short*)(wsb + 8388608);
  float* expo = (float*)(wsb + 8536064);
  float* s    = (float*)(wsb + 8536576);
  float* xinv = (float*)(wsb + 8798720);

  prep_wb<<<32, 256, 0, stream>>>(w, q, Wb);
  prep_expo<<<1, 128, 0, stream>>>(p, expo);
  prep_xt<<<1024, 256, 0, stream>>>(x, xT, s);
  prep_xinv<<<256, 256, 0, stream>>>(s, q, xinv);
  conv_mfma<<<512, 256, 0, stream>>>(xT, Wb, expo, xinv, out);
}

// Round 3
// 37.327 us; speedup vs baseline: 4.1197x; 1.1155x over previous
//
#include <hip/hip_runtime.h>
#include <math.h>
#include <stdint.h>

#define EPS 1e-12f

typedef __attribute__((ext_vector_type(8))) short short8v;   // 8 bf16 in 4 VGPRs
typedef __attribute__((ext_vector_type(8))) unsigned short us8;
typedef __attribute__((ext_vector_type(4))) float f32x4;

__device__ __forceinline__ unsigned short f2bf(float f) {
  union { float f; uint32_t u; } c; c.f = f;
  uint32_t u = c.u;
  uint32_t r = (u + 0x7FFFu + ((u >> 16) & 1u)) >> 16;  // RNE
  return (unsigned short)r;
}

__device__ __forceinline__ void gl_lds16(const void* g, void* l) {
  __builtin_amdgcn_global_load_lds(
      (const __attribute__((address_space(1))) unsigned int*)g,
      (__attribute__((address_space(3))) unsigned int*)l, 16, 0, 0);
}

// ---------------------------------------------------------------------------
// Workspace layout (bytes):
//   xT [16][64][64][64] bf16 @ 0        (8,388,608)  c-chunks XOR-swizzled by w&7
//   Wb [9][128][64] bf16    @ 8388608   (147,456)    c-chunks XOR-swizzled by v&7
//   s  [65536] f32          @ 8536064   (262,144)    per-pixel channel sq-sum
// ---------------------------------------------------------------------------

// Normalize weights, reorder to Wb[l][v][c] bf16 with chunk-XOR swizzle.
__global__ __launch_bounds__(256) void prep_wb(
    const float* __restrict__ w, const float* __restrict__ q,
    unsigned short* __restrict__ Wb) {
  int tid = threadIdx.x;
  int v = blockIdx.x * 4 + (tid >> 6);
  int c = tid & 63;
  float qn = q[0] * 0.01f;
  float scale = qn * qn;
  const float* wp = w + (v * 64 + c) * 9;
  float vals[9];
  float ss = 0.f;
#pragma unroll
  for (int j = 0; j < 9; ++j) { vals[j] = wp[j]; ss += vals[j] * vals[j]; }
#pragma unroll
  for (int off = 32; off > 0; off >>= 1) ss += __shfl_xor(ss, off);
  float inv = 1.0f / (sqrtf(ss + EPS) + scale);
  int pos = (((c >> 3) ^ (v & 7)) << 3) | (c & 7);
#pragma unroll
  for (int j = 0; j < 9; ++j) Wb[(j * 128 + v) * 64 + pos] = f2bf(vals[j] * inv);
}

// Transpose x[n][c][h][w] fp32 -> xT[n][h][w][c] bf16 (chunk-swizzled by w&7),
// fused per-pixel channel square-sum s[n,h,w].
__global__ __launch_bounds__(256) void prep_xt(
    const float* __restrict__ x, unsigned short* __restrict__ xT,
    float* __restrict__ s) {
  __shared__ float tile[64][65];
  int b = blockIdx.x;           // n*64 + h
  int n = b >> 6, h = b & 63;
  int tid = threadIdx.x;
  int c = tid >> 2, q = tid & 3;
  const float* xp = x + ((size_t)(n * 64 + c)) * 4096 + h * 64;
#pragma unroll
  for (int k = 0; k < 4; ++k) {
    int w0 = q * 16 + k * 4;
    float4 v4 = *(const float4*)(xp + w0);
    tile[c][w0 + 0] = v4.x; tile[c][w0 + 1] = v4.y;
    tile[c][w0 + 2] = v4.z; tile[c][w0 + 3] = v4.w;
  }
  __syncthreads();
  int w = tid >> 2;
  float ss = 0.f;
  unsigned short* orow = xT + ((size_t)(n * 4096 + h * 64 + w)) * 64;
#pragma unroll
  for (int t = 0; t < 2; ++t) {
    int slot = q * 2 + t;
    int lc = slot ^ (w & 7);          // logical chunk stored in this slot
    us8 st;
#pragma unroll
    for (int e = 0; e < 8; ++e) {
      float f = tile[lc * 8 + e][w];
      ss += f * f;
      st[e] = f2bf(f);
    }
    *(us8*)(orow + slot * 8) = st;
  }
  ss += __shfl_xor(ss, 1);
  ss += __shfl_xor(ss, 2);
  if (q == 0) s[n * 4096 + h * 64 + w] = ss;
}

// Main MFMA conv: block = 256 thr (4 waves), tile = 128 v x 128 pixels
// (2 h-rows x 64 w). K = 9 shifts x 64 c. Operand-swapped: D[pixel][v]
// so each lane holds 4 consecutive w per acc group -> float4 stores.
// xinv computed inline from s (box3x3) into LDS.
__global__ __launch_bounds__(256, 2) void conv_mfma(
    const unsigned short* __restrict__ xT, const unsigned short* __restrict__ Wb,
    const float* __restrict__ s, const float* __restrict__ p,
    const float* __restrict__ q, float* __restrict__ out) {
  __shared__ unsigned short xs[4 * 64 * 64];   // 4 h-rows x 64 w x 64 c, 32 KB
  __shared__ unsigned short wl[2 * 128 * 64];  // double-buffered weights, 32 KB
  __shared__ float xiv_lds[2][64];             // 1/(sqrt(box3x3(s))+scale)

  int b = blockIdx.x;            // 512 = 16 n x 32 row-pairs
  int n = b >> 5, hg = b & 31;
  int h0 = hg * 2;
  int tid = threadIdx.x;
  int lane = tid & 63, wid = tid >> 6;
  int wv = wid & 1, wp = wid >> 1;   // v-half, pixel-row
  int lp = lane & 15, lg = lane >> 4;

  // stage xs: wave wid stages tile row wid = image row h0-1+wid (zeros if OOB)
  {
    int hh = h0 - 1 + wid;
    unsigned short* dst = xs + wid * 4096;
    if (hh >= 0 && hh < 64) {
      const unsigned short* src = xT + ((size_t)(n * 4096 + hh * 64)) * 64;
#pragma unroll
      for (int i = 0; i < 8; ++i)
        gl_lds16(src + i * 512 + lane * 8, dst + i * 512);
    } else {
      us8 z = {};
#pragma unroll
      for (int i = 0; i < 8; ++i)
        *(us8*)(dst + i * 512 + lane * 8) = z;
    }
  }

  auto stage_w = [&](int bufi, int l) {
    const unsigned short* src = Wb + l * 8192 + wid * 2048;
    unsigned short* dst = wl + bufi * 8192 + wid * 2048;
#pragma unroll
    for (int i = 0; i < 4; ++i)
      gl_lds16(src + i * 512 + lane * 8, dst + i * 512);
  };
  stage_w(0, 0);

  // inline xinv for this block's 2 rows (threads 0..127)
  if (tid < 128) {
    int r = tid >> 6, w = tid & 63;
    int h = h0 + r;
    float qn = q[0] * 0.01f;
    float scale = qn * qn;
    const float* sp = s + n * 4096;
    float acc = 0.f;
#pragma unroll
    for (int dh = -1; dh <= 1; ++dh) {
      int hh = h + dh;
      if (hh >= 0 && hh < 64) {
#pragma unroll
        for (int dw = -1; dw <= 1; ++dw) {
          int ww = w + dw;
          if (ww >= 0 && ww < 64) acc += sp[hh * 64 + ww];
        }
      }
    }
    xiv_lds[r][w] = 1.0f / (sqrtf(acc + EPS) + scale);
  }

  f32x4 acc[4][4];   // [pg][vg]
#pragma unroll
  for (int i = 0; i < 4; ++i)
#pragma unroll
    for (int j = 0; j < 4; ++j) acc[i][j] = (f32x4){0.f, 0.f, 0.f, 0.f};

  __syncthreads();   // xs + wl[0] + xiv ready

  int buf = 0;
#pragma unroll
  for (int l = 0; l < 9; ++l) {
    if (l < 8) stage_w(buf ^ 1, l + 1);   // prefetch next shift's weights
    const int a = l / 3, bs = l % 3;
    const unsigned short* xrow = xs + (wp + a) * 4096;
    const unsigned short* wrow = wl + buf * 8192 + wv * 4096;
#pragma unroll
    for (int half = 0; half < 2; ++half) {
      const int cbase = half * 4;          // chunk index base (c0/8)
      short8v av[4], bv[4];
#pragma unroll
      for (int vg = 0; vg < 4; ++vg) {
        int vloc = vg * 16 + lp;           // v & 7 == lane & 7
        int slot = (cbase + lg) ^ (lane & 7);
        av[vg] = *(const short8v*)(wrow + vloc * 64 + slot * 8);
      }
#pragma unroll
      for (int pg = 0; pg < 4; ++pg) {
        int wx = pg * 16 + lp + bs - 1;
        bool ok = (unsigned)wx < 64u;
        int wxc = ok ? wx : (wx < 0 ? 0 : 63);
        int slot = (cbase + lg) ^ (wxc & 7);
        short8v t = *(const short8v*)(xrow + wxc * 64 + slot * 8);
        short8v z = {};
        bv[pg] = ok ? t : z;
      }
      // swapped operands: A = x (M=pixel), B = w (N=v) -> D[pixel][v]
#pragma unroll
      for (int pg = 0; pg < 4; ++pg)
#pragma unroll
        for (int vg = 0; vg < 4; ++vg)
          acc[pg][vg] = __builtin_amdgcn_mfma_f32_16x16x32_bf16(
              bv[pg], av[vg], acc[pg][vg], 0, 0, 0);
    }
    __syncthreads();
    buf ^= 1;
  }

  // epilogue: lane holds pixels w4..w4+3 (reg r), v = wv*64+vg*16+lp.
  int h = h0 + wp;
#pragma unroll
  for (int vg = 0; vg < 4; ++vg) {
    int v = wv * 64 + vg * 16 + lp;
    float t0 = p[v] * 0.1f;
    float e = t0 * t0;
    float* ob = out + ((size_t)(n * 128 + v)) * 4096 + h * 64;
#pragma unroll
    for (int pg = 0; pg < 4; ++pg) {
      int w4 = pg * 16 + lg * 4;
      float4 xv = *(const float4*)&xiv_lds[wp][w4];
      float4 o;
      float yv[4] = {acc[pg][vg][0] * xv.x, acc[pg][vg][1] * xv.y,
                     acc[pg][vg][2] * xv.z, acc[pg][vg][3] * xv.w};
      float* ov = (float*)&o;
#pragma unroll
      for (int r = 0; r < 4; ++r) {
        float y = yv[r];
        float t = fabsf(y) + EPS;
        float rv = exp2f(e * log2f(t));
        ov[r] = (y == 0.0f) ? 0.0f : copysignf(rv, y);
      }
      *(float4*)(ob + w4) = o;
    }
  }
}

extern "C" void kernel_launch(void* const* d_in, const int* in_sizes, int n_in,
                              void* d_out, int out_size, void* d_ws, size_t ws_size,
                              hipStream_t stream) {
  const float* x = (const float*)d_in[0];   // [16,64,64,64]
  const float* w = (const float*)d_in[1];   // [128,64,9]
  const float* p = (const float*)d_in[2];   // [128]
  const float* q = (const float*)d_in[3];   // [1]
  float* out = (float*)d_out;               // [16,128,64,64]

  char* wsb = (char*)d_ws;
  unsigned short* xT = (unsigned short*)(wsb);
  unsigned short* Wb = (unsigned short*)(wsb + 8388608);
  float* s = (float*)(wsb + 8536064);

  prep_wb<<<32, 256, 0, stream>>>(w, q, Wb);
  prep_xt<<<1024, 256, 0, stream>>>(x, xT, s);
  conv_mfma<<<512, 256, 0, stream>>>(xT, Wb, s, p, q, out);
}

// Round 4
// 29.642 us; speedup vs baseline: 5.1878x; 1.2593x over previous
//
#include <hip/hip_runtime.h>
#include <math.h>
#include <stdint.h>

#define EPS 1e-12f

typedef __attribute__((ext_vector_type(8))) short short8v;   // 8 bf16, 4 VGPRs
typedef __attribute__((ext_vector_type(8))) unsigned short us8;
typedef __attribute__((ext_vector_type(4))) float f32x4;

__device__ __forceinline__ unsigned short f2bf(float f) {
  union { float f; uint32_t u; } c; c.f = f;
  uint32_t u = c.u;
  uint32_t r = (u + 0x7FFFu + ((u >> 16) & 1u)) >> 16;  // RNE
  return (unsigned short)r;
}

// ---------------------------------------------------------------------------
// Workspace: Wb [9][128][64] bf16 @ 0 (147456 B), c-chunks XOR-swizzled by v&7
// ---------------------------------------------------------------------------

__global__ __launch_bounds__(256) void prep_wb(
    const float* __restrict__ w, const float* __restrict__ q,
    unsigned short* __restrict__ Wb) {
  int tid = threadIdx.x;
  int v = blockIdx.x * 4 + (tid >> 6);
  int c = tid & 63;
  float qn = q[0] * 0.01f;
  float scale = qn * qn;
  const float* wp = w + (v * 64 + c) * 9;
  float vals[9];
  float ss = 0.f;
#pragma unroll
  for (int j = 0; j < 9; ++j) { vals[j] = wp[j]; ss += vals[j] * vals[j]; }
#pragma unroll
  for (int off = 32; off > 0; off >>= 1) ss += __shfl_xor(ss, off);
  float inv = 1.0f / (sqrtf(ss + EPS) + scale);
  int pos = (((c >> 3) ^ (v & 7)) << 3) | (c & 7);
#pragma unroll
  for (int j = 0; j < 9; ++j) Wb[(j * 128 + v) * 64 + pos] = f2bf(vals[j] * inv);
}

// Fused conv: 256 blocks x 512 thr (8 waves). Tile = 4 h-rows x 64 w x 128 v.
// In-kernel: x fp32 -> bf16 transpose into swizzled LDS + channel sq-sum sf,
// box3x3 -> xiv, 9-shift MFMA loop (K = c), sharpen epilogue, float4 stores.
__global__ __launch_bounds__(512) void conv_fused(
    const float* __restrict__ x, const unsigned short* __restrict__ Wb,
    const float* __restrict__ p, const float* __restrict__ q,
    float* __restrict__ out) {
  __shared__ unsigned short xs[6 * 66 * 64];  // [row][w+1][c] 50688 B, padded w
  __shared__ unsigned short wl[128 * 64];     // one l-tile, 16384 B
  __shared__ float sf[6 * 64];                // channel sq-sums of staged rows
  __shared__ float xiv[4 * 64];               // 1/(sqrt(box3x3)+scale)

  int b = blockIdx.x;              // 256 = 16 n x 16 h-tiles
  int n = b >> 4, ht = b & 15;
  int h0 = ht * 4;
  int tid = threadIdx.x;
  int lane = tid & 63, wid = tid >> 6;
  int wv = wid & 1, wp = wid >> 1;     // v-half, output row
  int lp = lane & 15, lg = lane >> 4;

  // weight tile l=0 -> regs (issue before staging; LDS-write before barrier)
  const us8* wsrc = (const us8*)Wb + tid;   // + tid*8 shorts
  us8 wr0 = wsrc[0];
  us8 wr1 = wsrc[512];

  // ---- stage x rows h0-1 .. h0+4 (waves 0..5), pad columns (waves 6,7) ----
  if (wid < 6) {
    int hh = h0 - 1 + wid;
    int w = lane;
    unsigned short* xrow = xs + wid * 4224 + (w + 1) * 64;
    if ((unsigned)hh < 64u) {
      const float* xp = x + ((size_t)n << 18) + hh * 64 + w;
      float ss = 0.f;
#pragma unroll
      for (int j = 0; j < 8; ++j) {                 // c-chunk j: c = 8j..8j+7
        float v[8];
#pragma unroll
        for (int e = 0; e < 8; ++e) v[e] = xp[(j * 8 + e) * 4096];
        us8 pk;
#pragma unroll
        for (int e = 0; e < 8; ++e) { ss += v[e] * v[e]; pk[e] = f2bf(v[e]); }
        *(us8*)(xrow + ((j ^ (w & 7)) * 8)) = pk;   // swizzled by logical w
      }
      sf[wid * 64 + w] = ss;
    } else {
      us8 z = {};
#pragma unroll
      for (int j = 0; j < 8; ++j) *(us8*)(xrow + j * 8) = z;
      sf[wid * 64 + w] = 0.f;
    }
  } else {
    int t = tid - 384;                 // 0..127; need 96 zero-writes
    if (t < 96) {
      int row = t >> 4, side = (t >> 3) & 1, j = t & 7;
      us8 z = {};
      *(us8*)(xs + row * 4224 + (side ? 65 : 0) * 64 + j * 8) = z;
    }
  }
  us8* wl8 = (us8*)wl;
  wl8[tid] = wr0;
  wl8[tid + 512] = wr1;
  __syncthreads();   // xs, sf, wl(l=0) ready

  // ---- xiv for the 4 output rows (concurrent with early MFMA work) ----
  if (tid < 256) {
    int r = tid >> 6, w = tid & 63;
    float qn = q[0] * 0.01f;
    float scale = qn * qn;
    float a = 0.f;
#pragma unroll
    for (int dr = 0; dr < 3; ++dr) {
      const float* base = sf + (r + dr) * 64;
      a += base[w];
      if (w > 0) a += base[w - 1];
      if (w < 63) a += base[w + 1];
    }
    xiv[r * 64 + w] = 1.0f / (sqrtf(a + EPS) + scale);
  }

  f32x4 acc[4][4];   // [pg][vg]
#pragma unroll
  for (int i = 0; i < 4; ++i)
#pragma unroll
    for (int j = 0; j < 4; ++j) acc[i][j] = (f32x4){0.f, 0.f, 0.f, 0.f};

  const unsigned short* wbase = wl + wv * 4096;

#pragma unroll
  for (int l = 0; l < 9; ++l) {
    us8 nw0 = {}, nw1 = {};
    if (l < 8) {                       // T14: issue next tile's loads early
      nw0 = wsrc[(l + 1) * 1024];
      nw1 = wsrc[(l + 1) * 1024 + 512];
    }
    const int a = l / 3, bs = l % 3;
    const unsigned short* xrow = xs + (wp + a) * 4224;
#pragma unroll
    for (int half = 0; half < 2; ++half) {
      const int cbase = half * 4;
      short8v av[4], bv[4];
#pragma unroll
      for (int vg = 0; vg < 4; ++vg)
        av[vg] = *(const short8v*)(wbase + (vg * 16 + lp) * 64 +
                                   ((cbase + lg) ^ (lp & 7)) * 8);
#pragma unroll
      for (int pg = 0; pg < 4; ++pg) {
        int wx = pg * 16 + lp + bs - 1;          // -1..64; pad cols are zero
        bv[pg] = *(const short8v*)(xrow + (wx + 1) * 64 +
                                   ((cbase + lg) ^ (wx & 7)) * 8);
      }
#pragma unroll
      for (int pg = 0; pg < 4; ++pg)
#pragma unroll
        for (int vg = 0; vg < 4; ++vg)
          acc[pg][vg] = __builtin_amdgcn_mfma_f32_16x16x32_bf16(
              bv[pg], av[vg], acc[pg][vg], 0, 0, 0);
    }
    if (l < 8) {
      __syncthreads();                 // all waves done reading wl
      wl8[tid] = nw0;
      wl8[tid + 512] = nw1;
      __syncthreads();                 // wl holds tile l+1
    }
  }

  // ---- epilogue: D[pixel][v]; lane: w4 = pg*16+lg*4 (+r), v = wv*64+vg*16+lp
  int h = h0 + wp;
#pragma unroll
  for (int vg = 0; vg < 4; ++vg) {
    int v = wv * 64 + vg * 16 + lp;
    float t0 = p[v] * 0.1f;
    float e = t0 * t0;
    float* ob = out + ((size_t)(n * 128 + v)) * 4096 + h * 64;
#pragma unroll
    for (int pg = 0; pg < 4; ++pg) {
      int w4 = pg * 16 + lg * 4;
      float4 xv = *(const float4*)&xiv[wp * 64 + w4];
      float yv[4] = {acc[pg][vg][0] * xv.x, acc[pg][vg][1] * xv.y,
                     acc[pg][vg][2] * xv.z, acc[pg][vg][3] * xv.w};
      float4 o;
      float* ov = (float*)&o;
#pragma unroll
      for (int r = 0; r < 4; ++r) {
        float y = yv[r];
        float t = fabsf(y) + EPS;
        float rv = exp2f(e * log2f(t));
        ov[r] = (y == 0.0f) ? 0.0f : copysignf(rv, y);
      }
      *(float4*)(ob + w4) = o;
    }
  }
}

extern "C" void kernel_launch(void* const* d_in, const int* in_sizes, int n_in,
                              void* d_out, int out_size, void* d_ws, size_t ws_size,
                              hipStream_t stream) {
  const float* x = (const float*)d_in[0];   // [16,64,64,64]
  const float* w = (const float*)d_in[1];   // [128,64,9]
  const float* p = (const float*)d_in[2];   // [128]
  const float* q = (const float*)d_in[3];   // [1]
  float* out = (float*)d_out;               // [16,128,64,64]

  unsigned short* Wb = (unsigned short*)d_ws;

  prep_wb<<<32, 256, 0, stream>>>(w, q, Wb);
  conv_fused<<<256, 512, 0, stream>>>(x, Wb, p, q, out);
}